// Round 1
// 118.917 us; speedup vs baseline: 1.1620x; 1.1620x over previous
//
#include <hip/hip_runtime.h>

#define LOG2E 1.4426950408889634f

// Problem constants
constexpr int Bb = 4, LQ = 512, LK = 512, QS = 512, H = 256, DV = 512;
constexpr int M = 2048;   // B*LQ

// Workspace byte offsets
constexpr size_t OFF_EQT = 0;            // [256][2048] f32 (2 MiB) exp2-domain q proj
constexpr size_t OFF_EKT = 2u << 20;     // [256][2048] f32 (2 MiB)
constexpr size_t OFF_PQ  = 4u << 20;     // [4][512][512] bf16 (2 MiB) P numerators
constexpr size_t OFF_ROW = 6u << 20;     // [8][2048] f32 rowsum partials
constexpr size_t OFF_VT  = 8u << 20;     // [4][512][512] bf16 V^T ([b][n][k]) (2 MiB)

using bf16x8 = __attribute__((ext_vector_type(8))) short;
using f32x4v = __attribute__((ext_vector_type(4))) float;

__device__ inline unsigned short f2bf(float x) {
    unsigned int u = __float_as_uint(x);
    u += 0x7FFFu + ((u >> 16) & 1u);      // round-to-nearest-even
    return (unsigned short)(u >> 16);
}
// HW packed f32->bf16 (RNE, matches f2bf bit-for-bit on finite inputs).
// Replaces ~10 VALU of manual bit math with one instruction.
__device__ inline unsigned int pk2(float lo, float hi) {
    unsigned int r;
    asm("v_cvt_pk_bf16_f32 %0, %1, %2" : "=v"(r) : "v"(lo), "v"(hi));
    return r;
}

// ---------------------------------------------------------------------------
// Kernel A: proj via bf16 MFMA + exp2 epilogue, transposed fp32 output.
//   EqT[n][m] = exp2( clamp( scale*(A[m]·W[n] + bias[n]), ±15 ) )
// (unchanged structure; staging pack now uses v_cvt_pk_bf16_f32)
// ---------------------------------------------------------------------------
__global__ __launch_bounds__(256) void proj_mfma(
    const float* __restrict__ query, const float* __restrict__ key,
    const float* __restrict__ wq, const float* __restrict__ wk,
    const float* __restrict__ bq, const float* __restrict__ bk,
    char* __restrict__ ws, float scale)
{
    const int z = blockIdx.z;
    const float* A    = z ? key : query;   // [2048][512]
    const float* W    = z ? wk : wq;       // [256][512]
    const float* bias = z ? bk : bq;
    float* out = (float*)(ws + (z ? OFF_EKT : OFF_EQT));   // [256][2048]

    __shared__ unsigned short Als[64][136];
    __shared__ unsigned short Wls[64][136];
    __shared__ float Ot[64][68];

    const int mb = blockIdx.x * 64, nb = blockIdx.y * 64;
    const int tid = threadIdx.x;
    const int wid = tid >> 6, lane = tid & 63;
    const int ml = lane & 15, quad = lane >> 4;

    f32x4v acc[4] = {{0,0,0,0},{0,0,0,0},{0,0,0,0},{0,0,0,0}};

    for (int kc = 0; kc < QS; kc += 128) {
        __syncthreads();
#pragma unroll
        for (int it = 0; it < 4; ++it) {
            int u = tid + it * 256;          // 0..1023 units of 8 elems
            int row = u >> 4, c8 = (u & 15) * 8;
            float4 a0 = *(const float4*)(A + (size_t)(mb + row) * 512 + kc + c8);
            float4 a1 = *(const float4*)(A + (size_t)(mb + row) * 512 + kc + c8 + 4);
            uint4 pa = { pk2(a0.x, a0.y), pk2(a0.z, a0.w), pk2(a1.x, a1.y), pk2(a1.z, a1.w) };
            *(uint4*)&Als[row][c8] = pa;
            float4 w0 = *(const float4*)(W + (size_t)(nb + row) * 512 + kc + c8);
            float4 w1 = *(const float4*)(W + (size_t)(nb + row) * 512 + kc + c8 + 4);
            uint4 pw = { pk2(w0.x, w0.y), pk2(w0.z, w0.w), pk2(w1.x, w1.y), pk2(w1.z, w1.w) };
            *(uint4*)&Wls[row][c8] = pw;
        }
        __syncthreads();
#pragma unroll
        for (int s = 0; s < 4; ++s) {
            int k = s * 32 + quad * 8;
            bf16x8 af = *(const bf16x8*)&Als[wid * 16 + ml][k];
#pragma unroll
            for (int nt = 0; nt < 4; ++nt) {
                bf16x8 bfr = *(const bf16x8*)&Wls[nt * 16 + ml][k];
                acc[nt] = __builtin_amdgcn_mfma_f32_16x16x32_bf16(af, bfr, acc[nt], 0, 0, 0);
            }
        }
    }
    __syncthreads();
#pragma unroll
    for (int nt = 0; nt < 4; ++nt)
#pragma unroll
        for (int r = 0; r < 4; ++r)
            Ot[nt * 16 + ml][wid * 16 + quad * 4 + r] = acc[nt][r];
    __syncthreads();
    {
        int r0 = tid >> 2;            // n-local 0..63
        int c0 = (tid & 3) * 16;      // m-local base
        float bs = bias[nb + r0];
#pragma unroll
        for (int g = 0; g < 4; ++g) {
            float4 v = *(const float4*)&Ot[r0][c0 + g * 4];
            float4 o;
            o.x = __builtin_amdgcn_exp2f(fminf(fmaxf(scale * (v.x + bs), -15.f), 15.f));
            o.y = __builtin_amdgcn_exp2f(fminf(fmaxf(scale * (v.y + bs), -15.f), 15.f));
            o.z = __builtin_amdgcn_exp2f(fminf(fmaxf(scale * (v.z + bs), -15.f), 15.f));
            o.w = __builtin_amdgcn_exp2f(fminf(fmaxf(scale * (v.w + bs), -15.f), 15.f));
            *(float4*)(out + (size_t)(nb + r0) * 2048 + mb + c0 + g * 4) = o;
        }
    }
}

// ---------------------------------------------------------------------------
// Kernel A2 (new): V -> bf16 V^T [b][n][k], once.  Kills per-block scalar
// f2bf + conflicted ds_write_b16 transposition in av_mfma, halves V traffic.
// Same RNE rounding as before -> bit-identical V values in the MFMA.
// ---------------------------------------------------------------------------
__global__ __launch_bounds__(256) void vconv(
    const float* __restrict__ V, char* __restrict__ ws)
{
    unsigned short* VT = (unsigned short*)(ws + OFF_VT);
    __shared__ unsigned short T[64][72];
    const int b = blockIdx.z, k0 = blockIdx.x * 64, n0 = blockIdx.y * 64;
    const int tid = threadIdx.x;
    const float* Vb = V + (size_t)b * 512 * 512;
    const int r = tid >> 4, c = (tid & 15) * 4;
#pragma unroll
    for (int it = 0; it < 4; ++it) {
        int kr = r + it * 16;
        float4 v = *(const float4*)(Vb + (size_t)(k0 + kr) * 512 + n0 + c);
        T[c + 0][kr] = f2bf(v.x);
        T[c + 1][kr] = f2bf(v.y);
        T[c + 2][kr] = f2bf(v.z);
        T[c + 3][kr] = f2bf(v.w);
    }
    __syncthreads();
    const int rowO = tid >> 3, colO = (tid & 7) * 8;
#pragma unroll
    for (int it = 0; it < 2; ++it) {
        int n = rowO + it * 32;
        uint4 o = *(const uint4*)&T[n][colO];
        *(uint4*)(VT + ((size_t)b * 512 + n0 + n) * 512 + k0 + colO) = o;
    }
}

// ---------------------------------------------------------------------------
// Kernel B: scores -> P = exp2(-acc) bf16 [b][q][k] + per-ktile row partials.
//   acc(q,k) = sum_h Wv2[h]/(1 + Eq[h][q]*Ek[h][k])   (QUAD-paired, 1 rcp/4h)
// R15: 512-thread blocks (same 256-block grid, same 64x64 tile) -> 2
// waves/SIMD.  Previously exactly 1 wave/SIMD: all LDS latency, barrier
// drain and staging latency fully exposed.  Each thread now owns 4q x 2k.
// Math per (q,k) is accumulated in the identical order -> bit-identical acc.
// ---------------------------------------------------------------------------
__global__ __launch_bounds__(512, 2) void score_kernel(
    const float* __restrict__ wvp, char* __restrict__ ws)
{
    const float* EqT = (const float*)(ws + OFF_EQT);   // [256][2048]
    const float* EkT = (const float*)(ws + OFF_EKT);
    unsigned short* Pq = (unsigned short*)(ws + OFF_PQ);  // [4][512][512] bf16
    float* rowpart = (float*)(ws + OFF_ROW);              // [8][2048]

    __shared__ float Qs[64][64];
    __shared__ float Ks[64][64];
    __shared__ float Wv2[H];
    __shared__ float redS[8][64];

    const int b  = blockIdx.z;
    const int qb = blockIdx.x * 64;
    const int kt = blockIdx.y;
    const int kb = kt * 64;
    const int tid = threadIdx.x;
    const int tx = tid & 15;       // q frag: tx*4 + i
    const int ty = tid >> 4;       // k frag: ty*2 + j   (0..31)
    const int w  = tid >> 6;       // 0..7
    const int lane = tid & 63;

    if (tid < H) Wv2[tid] = wvp[tid] * (2.0f * LOG2E);

    const int mq = b * LQ + qb;
    const int mk = b * LK + kb;
    const int sh = tid >> 4;       // staging row 0..31 (+32 step)
    const int sm = (tid & 15) * 4;

    float acc[4][2] = {};

    for (int h0 = 0; h0 < H; h0 += 64) {
        __syncthreads();   // also covers the Wv2 write on the first pass
#pragma unroll
        for (int it = 0; it < 2; ++it) {
            int h = sh + 32 * it;
            *(float4*)&Qs[h][sm] = *(const float4*)(EqT + (size_t)(h0 + h) * M + mq + sm);
            *(float4*)&Ks[h][sm] = *(const float4*)(EkT + (size_t)(h0 + h) * M + mk + sm);
        }
        __syncthreads();
#pragma unroll 4
        for (int hh = 0; hh < 64; hh += 4) {
            float4 q1 = *(const float4*)&Qs[hh][tx * 4];
            float4 q2 = *(const float4*)&Qs[hh + 1][tx * 4];
            float4 q3 = *(const float4*)&Qs[hh + 2][tx * 4];
            float4 q4 = *(const float4*)&Qs[hh + 3][tx * 4];
            float2 k1 = *(const float2*)&Ks[hh][ty * 2];
            float2 k2 = *(const float2*)&Ks[hh + 1][ty * 2];
            float2 k3 = *(const float2*)&Ks[hh + 2][ty * 2];
            float2 k4 = *(const float2*)&Ks[hh + 3][ty * 2];
            float4 w4v = *(const float4*)&Wv2[h0 + hh];
            const float w1 = w4v.x, w2 = w4v.y, w3 = w4v.z, w4 = w4v.w;
            const float q1a[4] = {q1.x, q1.y, q1.z, q1.w};
            const float q2a[4] = {q2.x, q2.y, q2.z, q2.w};
            const float q3a[4] = {q3.x, q3.y, q3.z, q3.w};
            const float q4a[4] = {q4.x, q4.y, q4.z, q4.w};
            const float k1a[2] = {k1.x, k1.y};
            const float k2a[2] = {k2.x, k2.y};
            const float k3a[2] = {k3.x, k3.y};
            const float k4a[2] = {k4.x, k4.y};
#pragma unroll
            for (int i = 0; i < 4; ++i)
#pragma unroll
                for (int j = 0; j < 2; ++j) {
                    float ta = fmaf(q1a[i], k1a[j], 1.0f);
                    float tb = fmaf(q2a[i], k2a[j], 1.0f);
                    float tc = fmaf(q3a[i], k3a[j], 1.0f);
                    float td = fmaf(q4a[i], k4a[j], 1.0f);
                    float t12 = ta * tb;
                    float t34 = tc * td;
                    float n12 = fmaf(w1, tb, w2 * ta);
                    float n34 = fmaf(w3, td, w4 * tc);
                    float num = fmaf(n12, t34, n34 * t12);
                    float den = t12 * t34;
                    acc[i][j] = fmaf(num, __builtin_amdgcn_rcpf(den), acc[i][j]);
                }
        }
    }

    // Epilogue: P = exp2(-acc) -> bf16 Pq[b][q][kb+ty*2..+1]; row partials.
    float ps[4];
#pragma unroll
    for (int i = 0; i < 4; ++i) {
        int q = qb + tx * 4 + i;
        float p0 = __builtin_amdgcn_exp2f(-acc[i][0]);
        float p1 = __builtin_amdgcn_exp2f(-acc[i][1]);
        ps[i] = p0 + p1;
        *(unsigned int*)(Pq + ((size_t)(b * 512 + q) * 512 + kb + ty * 2)) = pk2(p0, p1);
    }
#pragma unroll
    for (int i = 0; i < 4; ++i) {
        ps[i] += __shfl_xor(ps[i], 16, 64);
        ps[i] += __shfl_xor(ps[i], 32, 64);
    }
    if (lane < 16) {
#pragma unroll
        for (int i = 0; i < 4; ++i) redS[w][tx * 4 + i] = ps[i];
    }
    __syncthreads();
    if (tid < 64) {
        float s = ((redS[0][tid] + redS[1][tid]) + (redS[2][tid] + redS[3][tid]))
                + ((redS[4][tid] + redS[5][tid]) + (redS[6][tid] + redS[7][tid]));
        rowpart[(size_t)kt * 2048 + b * 512 + qb + tid] = s;
    }
}

// ---------------------------------------------------------------------------
// Kernel C: out = (P @ V) / rowsum via bf16 MFMA.
// R15: 512-thread blocks (2 waves/SIMD); V staged from pre-converted bf16
// V^T with vector uint4 copies (no per-block convert / scalar LDS writes).
// Wave (wid&3) owns the m-subtile, (wid>>2) picks the nt half; MFMA
// accumulation order per output element is unchanged -> bit-identical.
// ---------------------------------------------------------------------------
__global__ __launch_bounds__(512, 2) void av_mfma(
    const char* __restrict__ wsc, float* __restrict__ O)
{
    const unsigned short* Pq = (const unsigned short*)(wsc + OFF_PQ);
    const unsigned short* VT = (const unsigned short*)(wsc + OFF_VT);
    const float* rowpart = (const float*)(wsc + OFF_ROW);

    __shared__ unsigned short Pls[64][136];
    __shared__ unsigned short Vls[64][136];

    const int b = blockIdx.z, qb = blockIdx.x * 64, nb = blockIdx.y * 64;
    const int tid = threadIdx.x;
    const int wid = tid >> 6, lane = tid & 63;
    const int ml = lane & 15, quad = lane >> 4;
    const int ms = wid & 3, nh = wid >> 2;     // m-subtile, nt-half
    const unsigned short* Pb = Pq + (size_t)b * 512 * 512;
    const unsigned short* Vb = VT + (size_t)b * 512 * 512;

    f32x4v acc[2] = {{0,0,0,0},{0,0,0,0}};

    for (int kc = 0; kc < LK; kc += 128) {
        __syncthreads();
#pragma unroll
        for (int it = 0; it < 2; ++it) {
            int u = tid + it * 512;
            int row = u >> 4, c8 = (u & 15) * 8;
            *(uint4*)&Pls[row][c8] = *(const uint4*)(Pb + (size_t)(qb + row) * 512 + kc + c8);
            *(uint4*)&Vls[row][c8] = *(const uint4*)(Vb + (size_t)(nb + row) * 512 + kc + c8);
        }
        __syncthreads();
#pragma unroll
        for (int s = 0; s < 4; ++s) {
            int k = s * 32 + quad * 8;
            bf16x8 af = *(const bf16x8*)&Pls[ms * 16 + ml][k];
#pragma unroll
            for (int t = 0; t < 2; ++t) {
                bf16x8 bfr = *(const bf16x8*)&Vls[(nh * 2 + t) * 16 + ml][k];
                acc[t] = __builtin_amdgcn_mfma_f32_16x16x32_bf16(af, bfr, acc[t], 0, 0, 0);
            }
        }
    }

    float rr[4];
#pragma unroll
    for (int r = 0; r < 4; ++r) {
        int q = qb + ms * 16 + quad * 4 + r;
        float rs = 0.f;
#pragma unroll
        for (int t8 = 0; t8 < 8; ++t8) rs += rowpart[(size_t)t8 * 2048 + b * 512 + q];
        rr[r] = 1.0f / rs;
    }
#pragma unroll
    for (int t = 0; t < 2; ++t)
#pragma unroll
        for (int r = 0; r < 4; ++r) {
            int q = qb + ms * 16 + quad * 4 + r;
            O[((size_t)b * 512 + q) * 512 + nb + (nh * 2 + t) * 16 + ml] = acc[t][r] * rr[r];
        }
}

extern "C" void kernel_launch(void* const* d_in, const int* in_sizes, int n_in,
                              void* d_out, int out_size, void* d_ws, size_t ws_size,
                              hipStream_t stream) {
    const float* query = (const float*)d_in[0];
    const float* key   = (const float*)d_in[1];
    const float* value = (const float*)d_in[2];
    const float* wq    = (const float*)d_in[3];
    const float* bq    = (const float*)d_in[4];
    const float* wk    = (const float*)d_in[5];
    const float* bk    = (const float*)d_in[6];
    const float* wv    = (const float*)d_in[7];
    // d_in[8] = bv: row-constant -> softmax-invariant, dropped.
    float* out = (float*)d_out;
    char* ws = (char*)d_ws;

    const float c2 = 2.0f * LOG2E;

    proj_mfma<<<dim3(32, 4, 2), 256, 0, stream>>>(query, key, wq, wk, bq, bk, ws, c2);
    vconv<<<dim3(8, 8, Bb), 256, 0, stream>>>(value, ws);
    score_kernel<<<dim3(8, 8, Bb), 512, 0, stream>>>(wv, ws);
    av_mfma<<<dim3(8, 8, Bb), 512, 0, stream>>>(ws, out);
}

// Round 2
// 118.659 us; speedup vs baseline: 1.1645x; 1.0022x over previous
//
#include <hip/hip_runtime.h>

#define LOG2E 1.4426950408889634f

// Problem constants
constexpr int Bb = 4, LQ = 512, LK = 512, QS = 512, H = 256, DV = 512;
constexpr int M = 2048;   // B*LQ

// Workspace byte offsets
constexpr size_t OFF_EQT = 0;            // [256][2048] f32 (2 MiB) exp2-domain q proj (pre-scaled by 2^-13)
constexpr size_t OFF_EKT = 2u << 20;     // [256][2048] f32 (2 MiB)
constexpr size_t OFF_PQ  = 4u << 20;     // [4][512][512] bf16 (2 MiB) P numerators
constexpr size_t OFF_ROW = 6u << 20;     // [8][2048] f32 rowsum partials
constexpr size_t OFF_VT  = 8u << 20;     // [4][512][512] bf16 V^T ([b][n][k]) (2 MiB)

using bf16x8 = __attribute__((ext_vector_type(8))) short;
using f32x4v = __attribute__((ext_vector_type(4))) float;

__device__ inline unsigned short f2bf(float x) {
    unsigned int u = __float_as_uint(x);
    u += 0x7FFFu + ((u >> 16) & 1u);      // round-to-nearest-even
    return (unsigned short)(u >> 16);
}
// HW packed f32->bf16 (RNE, matches f2bf bit-for-bit on finite inputs).
__device__ inline unsigned int pk2(float lo, float hi) {
    unsigned int r;
    asm("v_cvt_pk_bf16_f32 %0, %1, %2" : "=v"(r) : "v"(lo), "v"(hi));
    return r;
}

// ---------------------------------------------------------------------------
// Kernel A: proj via bf16 MFMA + exp2 epilogue, transposed fp32 output.
//   EqT[n][m] = exp2( clamp( scale*(A[m]·W[n] + bias[n]), ±13 ) - 13 )  (z=0)
//   EkT[n][m] = exp2( clamp( ..., ±13 ) )                                (z=1)
// R16: clamp 15->13 and Eq pre-scaled by 2^-13 so the score kernel can do
// 8-way rcp pairing without fp32 overflow (den8 <= 2^52).  tanh saturates
// at |x|=4.5 -> err 2.5e-4 on ~0.07% of elems, x wv<=1/16 -> ~3e-6 on
// scores.  Negligible.
// ---------------------------------------------------------------------------
__global__ __launch_bounds__(256) void proj_mfma(
    const float* __restrict__ query, const float* __restrict__ key,
    const float* __restrict__ wq, const float* __restrict__ wk,
    const float* __restrict__ bq, const float* __restrict__ bk,
    char* __restrict__ ws, float scale)
{
    const int z = blockIdx.z;
    const float* A    = z ? key : query;   // [2048][512]
    const float* W    = z ? wk : wq;       // [256][512]
    const float* bias = z ? bk : bq;
    float* out = (float*)(ws + (z ? OFF_EKT : OFF_EQT));   // [256][2048]
    const float off = z ? 0.0f : 13.0f;

    __shared__ unsigned short Als[64][136];
    __shared__ unsigned short Wls[64][136];
    __shared__ float Ot[64][68];

    const int mb = blockIdx.x * 64, nb = blockIdx.y * 64;
    const int tid = threadIdx.x;
    const int wid = tid >> 6, lane = tid & 63;
    const int ml = lane & 15, quad = lane >> 4;

    f32x4v acc[4] = {{0,0,0,0},{0,0,0,0},{0,0,0,0},{0,0,0,0}};

    for (int kc = 0; kc < QS; kc += 128) {
        __syncthreads();
#pragma unroll
        for (int it = 0; it < 4; ++it) {
            int u = tid + it * 256;          // 0..1023 units of 8 elems
            int row = u >> 4, c8 = (u & 15) * 8;
            float4 a0 = *(const float4*)(A + (size_t)(mb + row) * 512 + kc + c8);
            float4 a1 = *(const float4*)(A + (size_t)(mb + row) * 512 + kc + c8 + 4);
            uint4 pa = { pk2(a0.x, a0.y), pk2(a0.z, a0.w), pk2(a1.x, a1.y), pk2(a1.z, a1.w) };
            *(uint4*)&Als[row][c8] = pa;
            float4 w0 = *(const float4*)(W + (size_t)(nb + row) * 512 + kc + c8);
            float4 w1 = *(const float4*)(W + (size_t)(nb + row) * 512 + kc + c8 + 4);
            uint4 pw = { pk2(w0.x, w0.y), pk2(w0.z, w0.w), pk2(w1.x, w1.y), pk2(w1.z, w1.w) };
            *(uint4*)&Wls[row][c8] = pw;
        }
        __syncthreads();
#pragma unroll
        for (int s = 0; s < 4; ++s) {
            int k = s * 32 + quad * 8;
            bf16x8 af = *(const bf16x8*)&Als[wid * 16 + ml][k];
#pragma unroll
            for (int nt = 0; nt < 4; ++nt) {
                bf16x8 bfr = *(const bf16x8*)&Wls[nt * 16 + ml][k];
                acc[nt] = __builtin_amdgcn_mfma_f32_16x16x32_bf16(af, bfr, acc[nt], 0, 0, 0);
            }
        }
    }
    __syncthreads();
#pragma unroll
    for (int nt = 0; nt < 4; ++nt)
#pragma unroll
        for (int r = 0; r < 4; ++r)
            Ot[nt * 16 + ml][wid * 16 + quad * 4 + r] = acc[nt][r];
    __syncthreads();
    {
        int r0 = tid >> 2;            // n-local 0..63
        int c0 = (tid & 3) * 16;      // m-local base
        float bs = bias[nb + r0];
#pragma unroll
        for (int g = 0; g < 4; ++g) {
            float4 v = *(const float4*)&Ot[r0][c0 + g * 4];
            float4 o;
            o.x = __builtin_amdgcn_exp2f(fminf(fmaxf(scale * (v.x + bs), -13.f), 13.f) - off);
            o.y = __builtin_amdgcn_exp2f(fminf(fmaxf(scale * (v.y + bs), -13.f), 13.f) - off);
            o.z = __builtin_amdgcn_exp2f(fminf(fmaxf(scale * (v.z + bs), -13.f), 13.f) - off);
            o.w = __builtin_amdgcn_exp2f(fminf(fmaxf(scale * (v.w + bs), -13.f), 13.f) - off);
            *(float4*)(out + (size_t)(nb + r0) * 2048 + mb + c0 + g * 4) = o;
        }
    }
}

// ---------------------------------------------------------------------------
// Kernel A2: V -> bf16 V^T [b][n][k], once.  (unchanged from R15)
// ---------------------------------------------------------------------------
__global__ __launch_bounds__(256) void vconv(
    const float* __restrict__ V, char* __restrict__ ws)
{
    unsigned short* VT = (unsigned short*)(ws + OFF_VT);
    __shared__ unsigned short T[64][72];
    const int b = blockIdx.z, k0 = blockIdx.x * 64, n0 = blockIdx.y * 64;
    const int tid = threadIdx.x;
    const float* Vb = V + (size_t)b * 512 * 512;
    const int r = tid >> 4, c = (tid & 15) * 4;
#pragma unroll
    for (int it = 0; it < 4; ++it) {
        int kr = r + it * 16;
        float4 v = *(const float4*)(Vb + (size_t)(k0 + kr) * 512 + n0 + c);
        T[c + 0][kr] = f2bf(v.x);
        T[c + 1][kr] = f2bf(v.y);
        T[c + 2][kr] = f2bf(v.z);
        T[c + 3][kr] = f2bf(v.w);
    }
    __syncthreads();
    const int rowO = tid >> 3, colO = (tid & 7) * 8;
#pragma unroll
    for (int it = 0; it < 2; ++it) {
        int n = rowO + it * 32;
        uint4 o = *(const uint4*)&T[n][colO];
        *(uint4*)(VT + ((size_t)b * 512 + n0 + n) * 512 + k0 + colO) = o;
    }
}

// ---------------------------------------------------------------------------
// Kernel B: scores -> P = exp2(-acc) bf16 [b][q][k] + per-ktile row partials.
//   acc(q,k) = sum_h Wv2[h]/(1 + Eq[h][q]*Ek[h][k])
// R16: 8-way rcp pairing.  With t~ = s*t (s=2^-13, folded into stored Eq
// via the proj -13 offset, zero extra ops) and Wv2~ = s*Wv2:
//   NUM~ = s^8*NUM, DEN~ = s^8*DEN  ->  NUM~/DEN~ exact.
//   DEN~ in [2^-52, 2^52]; NUM~ >= ~2^-104 -> no overflow/denormals.
// Per 8h per elem: 30 VALU + 1 rcp (vs 28 + 2) -> -13.6% issue cycles.
// Also: tile 32q x 64k, grid (16,8,4)=512 blocks x 512 thr -> 2 blocks/CU,
// 4 waves/SIMD, INDEPENDENT barriers (1-block/CU grids stall all waves at
// each chunk barrier together).
// ---------------------------------------------------------------------------
__global__ __launch_bounds__(512, 4) void score_kernel(
    const float* __restrict__ wvp, char* __restrict__ ws)
{
    const float* EqT = (const float*)(ws + OFF_EQT);   // [256][2048], pre-scaled 2^-13
    const float* EkT = (const float*)(ws + OFF_EKT);
    unsigned short* Pq = (unsigned short*)(ws + OFF_PQ);  // [4][512][512] bf16
    float* rowpart = (float*)(ws + OFF_ROW);              // [8][2048]

    __shared__ float Qs[64][32];
    __shared__ float Ks[64][64];
    __shared__ float Wv2[H];
    __shared__ float redS[8][32];

    const int b  = blockIdx.z;
    const int qb = blockIdx.x * 32;
    const int kt = blockIdx.y;
    const int kb = kt * 64;
    const int tid = threadIdx.x;
    const int tx = tid & 15;       // q frag: tx*2 + i
    const int ty = tid >> 4;       // k frag: ty*2 + j   (0..31)
    const int w  = tid >> 6;       // 0..7
    const int lane = tid & 63;

    constexpr float S = 0.0001220703125f;   // 2^-13
    if (tid < H) Wv2[tid] = wvp[tid] * (2.0f * LOG2E) * S;   // fold one s into w

    const int mq = b * LQ + qb;
    const int mk = b * LK + kb;

    float acc[2][2] = {};

    for (int h0 = 0; h0 < H; h0 += 64) {
        __syncthreads();   // also covers the Wv2 write on the first pass
        {
            int hq = tid >> 3, cq = (tid & 7) * 4;
            *(float4*)&Qs[hq][cq] = *(const float4*)(EqT + (size_t)(h0 + hq) * M + mq + cq);
            int hk = tid >> 4, ck = (tid & 15) * 4;
            *(float4*)&Ks[hk][ck]      = *(const float4*)(EkT + (size_t)(h0 + hk) * M + mk + ck);
            *(float4*)&Ks[hk + 32][ck] = *(const float4*)(EkT + (size_t)(h0 + hk + 32) * M + mk + ck);
        }
        __syncthreads();
#pragma unroll 2
        for (int hh = 0; hh < 64; hh += 8) {
            float2 qv[8], kv[8];
#pragma unroll
            for (int u = 0; u < 8; ++u) qv[u] = *(const float2*)&Qs[hh + u][tx * 2];
#pragma unroll
            for (int u = 0; u < 8; ++u) kv[u] = *(const float2*)&Ks[hh + u][ty * 2];
            const float4 wA = *(const float4*)&Wv2[h0 + hh];
            const float4 wB = *(const float4*)&Wv2[h0 + hh + 4];
#pragma unroll
            for (int i = 0; i < 2; ++i)
#pragma unroll
                for (int j = 0; j < 2; ++j) {
                    float t[8];
#pragma unroll
                    for (int u = 0; u < 8; ++u)
                        t[u] = fmaf(i ? qv[u].y : qv[u].x, j ? kv[u].y : kv[u].x, S);
                    float t12 = t[0] * t[1], t34 = t[2] * t[3];
                    float n12 = fmaf(wA.x, t[1], wA.y * t[0]);
                    float n34 = fmaf(wA.z, t[3], wA.w * t[2]);
                    float numA = fmaf(n12, t34, n34 * t12);
                    float denA = t12 * t34;
                    float t56 = t[4] * t[5], t78 = t[6] * t[7];
                    float m12 = fmaf(wB.x, t[5], wB.y * t[4]);
                    float m34 = fmaf(wB.z, t[7], wB.w * t[6]);
                    float numB = fmaf(m12, t78, m34 * t56);
                    float denB = t56 * t78;
                    float NUMv = fmaf(numA, denB, numB * denA);
                    float DENv = denA * denB;
                    acc[i][j] = fmaf(NUMv, __builtin_amdgcn_rcpf(DENv), acc[i][j]);
                }
        }
    }

    // Epilogue: P = exp2(-acc) -> bf16 Pq[b][q][kb+ty*2..+1]; row partials.
    float ps[2];
#pragma unroll
    for (int i = 0; i < 2; ++i) {
        int q = qb + tx * 2 + i;
        float p0 = __builtin_amdgcn_exp2f(-acc[i][0]);
        float p1 = __builtin_amdgcn_exp2f(-acc[i][1]);
        ps[i] = p0 + p1;
        *(unsigned int*)(Pq + ((size_t)(b * 512 + q) * 512 + kb + ty * 2)) = pk2(p0, p1);
    }
#pragma unroll
    for (int i = 0; i < 2; ++i) {
        ps[i] += __shfl_xor(ps[i], 16, 64);
        ps[i] += __shfl_xor(ps[i], 32, 64);
    }
    if (lane < 16) {
#pragma unroll
        for (int i = 0; i < 2; ++i) redS[w][tx * 2 + i] = ps[i];
    }
    __syncthreads();
    if (tid < 32) {
        float s = ((redS[0][tid] + redS[1][tid]) + (redS[2][tid] + redS[3][tid]))
                + ((redS[4][tid] + redS[5][tid]) + (redS[6][tid] + redS[7][tid]));
        rowpart[(size_t)kt * 2048 + b * 512 + qb + tid] = s;
    }
}

// ---------------------------------------------------------------------------
// Kernel C: out = (P @ V) / rowsum via bf16 MFMA.  (unchanged from R15)
// ---------------------------------------------------------------------------
__global__ __launch_bounds__(512, 2) void av_mfma(
    const char* __restrict__ wsc, float* __restrict__ O)
{
    const unsigned short* Pq = (const unsigned short*)(wsc + OFF_PQ);
    const unsigned short* VT = (const unsigned short*)(wsc + OFF_VT);
    const float* rowpart = (const float*)(wsc + OFF_ROW);

    __shared__ unsigned short Pls[64][136];
    __shared__ unsigned short Vls[64][136];

    const int b = blockIdx.z, qb = blockIdx.x * 64, nb = blockIdx.y * 64;
    const int tid = threadIdx.x;
    const int wid = tid >> 6, lane = tid & 63;
    const int ml = lane & 15, quad = lane >> 4;
    const int ms = wid & 3, nh = wid >> 2;     // m-subtile, nt-half
    const unsigned short* Pb = Pq + (size_t)b * 512 * 512;
    const unsigned short* Vb = VT + (size_t)b * 512 * 512;

    f32x4v acc[2] = {{0,0,0,0},{0,0,0,0}};

    for (int kc = 0; kc < LK; kc += 128) {
        __syncthreads();
#pragma unroll
        for (int it = 0; it < 2; ++it) {
            int u = tid + it * 512;
            int row = u >> 4, c8 = (u & 15) * 8;
            *(uint4*)&Pls[row][c8] = *(const uint4*)(Pb + (size_t)(qb + row) * 512 + kc + c8);
            *(uint4*)&Vls[row][c8] = *(const uint4*)(Vb + (size_t)(nb + row) * 512 + kc + c8);
        }
        __syncthreads();
#pragma unroll
        for (int s = 0; s < 4; ++s) {
            int k = s * 32 + quad * 8;
            bf16x8 af = *(const bf16x8*)&Pls[ms * 16 + ml][k];
#pragma unroll
            for (int t = 0; t < 2; ++t) {
                bf16x8 bfr = *(const bf16x8*)&Vls[(nh * 2 + t) * 16 + ml][k];
                acc[t] = __builtin_amdgcn_mfma_f32_16x16x32_bf16(af, bfr, acc[t], 0, 0, 0);
            }
        }
    }

    float rr[4];
#pragma unroll
    for (int r = 0; r < 4; ++r) {
        int q = qb + ms * 16 + quad * 4 + r;
        float rs = 0.f;
#pragma unroll
        for (int t8 = 0; t8 < 8; ++t8) rs += rowpart[(size_t)t8 * 2048 + b * 512 + q];
        rr[r] = 1.0f / rs;
    }
#pragma unroll
    for (int t = 0; t < 2; ++t)
#pragma unroll
        for (int r = 0; r < 4; ++r) {
            int q = qb + ms * 16 + quad * 4 + r;
            O[((size_t)b * 512 + q) * 512 + nb + (nh * 2 + t) * 16 + ml] = acc[t][r] * rr[r];
        }
}

extern "C" void kernel_launch(void* const* d_in, const int* in_sizes, int n_in,
                              void* d_out, int out_size, void* d_ws, size_t ws_size,
                              hipStream_t stream) {
    const float* query = (const float*)d_in[0];
    const float* key   = (const float*)d_in[1];
    const float* value = (const float*)d_in[2];
    const float* wq    = (const float*)d_in[3];
    const float* bq    = (const float*)d_in[4];
    const float* wk    = (const float*)d_in[5];
    const float* bk    = (const float*)d_in[6];
    const float* wv    = (const float*)d_in[7];
    // d_in[8] = bv: row-constant -> softmax-invariant, dropped.
    float* out = (float*)d_out;
    char* ws = (char*)d_ws;

    const float c2 = 2.0f * LOG2E;

    proj_mfma<<<dim3(32, 4, 2), 256, 0, stream>>>(query, key, wq, wk, bq, bk, ws, c2);
    vconv<<<dim3(8, 8, Bb), 256, 0, stream>>>(value, ws);
    score_kernel<<<dim3(16, 8, Bb), 512, 0, stream>>>(wv, ws);
    av_mfma<<<dim3(8, 8, Bb), 512, 0, stream>>>(ws, out);
}